// Round 4
// baseline (469.625 us; speedup 1.0000x reference)
//
#include <hip/hip_runtime.h>
#include <math.h>

#define CC 96
#define NP 4096          // 64*64
#define NHEADS 6
#define NELEMF 393216.0f // C*H*W per batch
#define EPSF 1e-5f

// ---- workspace layout (float offsets) ----
#define WS_STATS 0
#define WS_W1T   64                    // mlp_w1^T  (96 x 384)
#define WS_W2T   (WS_W1T + 36864)      // mlp_w2^T  (384 x 96)
#define WS_M2A1T (WS_W2T + 36864)      // m2a_w1^T  (96 x 96)
#define WS_M2A2T (WS_M2A1T + 9216)     // m2a_w2^T  (96 x 96)
#define WS_PA1T  (WS_M2A2T + 9216)     // pa_w1^T   (96 x 12)
#define WS_BNS   (WS_PA1T + 1152)      // bn scale[96] + shift[96]
#define WS_Q     (WS_BNS + 192 + 32)
#define WS_K     (WS_Q + 1572864)
#define WS_V     (WS_K + 1572864)
#define WS_ATT   (WS_V + 1572864)
#define WS_X1    (WS_ATT + 1572864)    // hid reuses WS_Q..WS_X1
#define WS_X2    (WS_X1 + 1572864)
#define WS_X3    (WS_X2 + 1572864)
#define WS_PAB   (WS_X3 + 1572864)
#define WS_GAP   (WS_PAB + 16384)
#define WS_CA    (WS_GAP + 384)

__device__ __forceinline__ float gelu_f(float x){
  return 0.5f * x * (1.0f + erff(x * 0.7071067811865476f));
}
__device__ __forceinline__ float sigmoid_f(float x){
  return 1.0f / (1.0f + __expf(-x));
}
__device__ __forceinline__ void get_ms(const float* st, int b, float& mean, float& inv, float& stdv){
  float s = st[b], s2 = st[4+b];
  mean = s * (1.0f/NELEMF);
  float var = fmaxf(s2 * (1.0f/NELEMF) - mean*mean, 0.0f);
  stdv = sqrtf(var + EPSF);
  inv = 1.0f / stdv;
}

// ---- per-batch sum/sumsq (input x only; x1/x2 stats fused into proj) ----
__global__ void stats_kernel(const float* __restrict__ src, float* __restrict__ st){
  int b = blockIdx.x / CC, c = blockIdx.x % CC;
  const float* p = src + (b*CC + c)*NP;
  float s = 0.f, s2 = 0.f;
  for(int i = threadIdx.x; i < NP; i += 256){ float v = p[i]; s += v; s2 = fmaf(v, v, s2); }
  for(int off = 32; off > 0; off >>= 1){ s += __shfl_down(s, off); s2 += __shfl_down(s2, off); }
  __shared__ float ls[8];
  int wid = threadIdx.x >> 6;
  if((threadIdx.x & 63) == 0){ ls[wid] = s; ls[4+wid] = s2; }
  __syncthreads();
  if(threadIdx.x == 0){
    atomicAdd(&st[b],   ls[0]+ls[1]+ls[2]+ls[3]);
    atomicAdd(&st[4+b], ls[4]+ls[5]+ls[6]+ls[7]);
  }
}

// ---- transpose small weights + BN scale/shift into ws ----
__global__ void prep_weights(const float* __restrict__ w1, const float* __restrict__ w2,
                             const float* __restrict__ a1, const float* __restrict__ a2,
                             const float* __restrict__ pw1,
                             const float* __restrict__ bg, const float* __restrict__ bb,
                             const float* __restrict__ bm, const float* __restrict__ bv,
                             float* __restrict__ ws){
  int gid = blockIdx.x*256 + threadIdx.x;
  if(gid < 36864){ int r = gid/96, c = gid%96; ws[WS_W1T + c*384 + r] = w1[gid]; }
  else if(gid < 73728){ int g = gid-36864; int r = g/384, c = g%384; ws[WS_W2T + c*96 + r] = w2[g]; }
  else if(gid < 82944){ int g = gid-73728; int r = g/96, c = g%96; ws[WS_M2A1T + c*96 + r] = a1[g]; }
  else if(gid < 92160){ int g = gid-82944; int r = g/96, c = g%96; ws[WS_M2A2T + c*96 + r] = a2[g]; }
  else if(gid < 93312){ int g = gid-92160; int r = g/96, c = g%96; ws[WS_PA1T + c*12 + r] = pw1[g]; }
  else if(gid < 93408){ int c = gid-93312;
    float sc = rsqrtf(bv[c] + EPSF) * bg[c];
    ws[WS_BNS + c] = sc;
    ws[WS_BNS + 96 + c] = bb[c] - bm[c]*sc;
  }
}

// ---- QKV projection with fused LN: 32 outputs/thread ----
__global__ void __launch_bounds__(256) gemm_qkv_kernel(
    const float* __restrict__ xin, const float* __restrict__ st,
    const float* __restrict__ lnw, const float* __restrict__ lnb,
    const float* __restrict__ qw, const float* __restrict__ qb,
    float* __restrict__ qo, float* __restrict__ ko, float* __restrict__ vo){
  int b = blockIdx.x >> 4, pix = (blockIdx.x & 15)*256 + threadIdx.x;
  int n0 = blockIdx.y * 32;
  float mean, inv, stdv; get_ms(st, b, mean, inv, stdv);
  const float* act = xin + b*CC*NP + pix;
  float4 acc[8];
  #pragma unroll
  for(int j = 0; j < 8; ++j) acc[j] = make_float4(0,0,0,0);
  #pragma unroll 4
  for(int c = 0; c < CC; ++c){
    float s = inv * lnw[c];
    float o = lnb[c] - mean * s;
    float a = fmaf(act[c*NP], s, o);
    #pragma unroll
    for(int j = 0; j < 8; ++j){
      float4 wv = *(const float4*)(qw + c*288 + n0 + j*4);
      acc[j].x = fmaf(a, wv.x, acc[j].x); acc[j].y = fmaf(a, wv.y, acc[j].y);
      acc[j].z = fmaf(a, wv.z, acc[j].z); acc[j].w = fmaf(a, wv.w, acc[j].w);
    }
  }
  int t = n0 / 96;
  float scale = (t == 0) ? 0.25f : 1.0f;
  float* dst = (t == 0) ? qo : (t == 1) ? ko : vo;
  #pragma unroll
  for(int j = 0; j < 8; ++j){
    int o = n0 + j*4;
    int head = (o % 96) >> 4, d = o & 15;
    float4 bias = *(const float4*)(qb + o);
    float4 r;
    r.x = (acc[j].x + bias.x)*scale; r.y = (acc[j].y + bias.y)*scale;
    r.z = (acc[j].z + bias.z)*scale; r.w = (acc[j].w + bias.w)*scale;
    *(float4*)(dst + ((b*NHEADS + head)*NP + pix)*16 + d) = r;
  }
}

// ---- neighborhood attention: LDS-staged k/v rows (shared by all pixels of row x) ----
template<int K, int D, int RPB>
__global__ void __launch_bounds__(256) attn_kernel(
    const float* __restrict__ qb, const float* __restrict__ kb,
    const float* __restrict__ vb, const float* __restrict__ rpb,
    float* __restrict__ outp){
  int bh = blockIdx.x >> 6;
  int x = blockIdx.x & 63;
  int head = bh % NHEADS, b = bh / NHEADS;

  int gx = x % D, px = x / D;
  int Lgx = (64 - gx + D - 1) / D;
  int sx = min(max(px - K/2, 0), Lgx - K);

  __shared__ float sm[2*K*1024];
  float* kl = sm;
  float* vl = sm + K*1024;
  const float* kg = kb + bh*NP*16;
  const float* vg = vb + bh*NP*16;
  int tid = threadIdx.x;
  #pragma unroll
  for(int i = 0; i < K; ++i){
    int hh = gx + D*(sx + i);
    ((float4*)(kl + i*1024))[tid] = ((const float4*)(kg + hh*1024))[tid];
    ((float4*)(vl + i*1024))[tid] = ((const float4*)(vg + hh*1024))[tid];
  }
  __syncthreads();

  int pixoff = tid >> 2, t = tid & 3;
  int y = pixoff;
  int pix = x*64 + y;
  const float4 q = *(const float4*)(qb + (bh*NP + pix)*16 + 4*t);

  int gy = y % D, py = y / D;
  int Lgy = (64 - gy + D - 1) / D;
  int sy = min(max(py - K/2, 0), Lgy - K);

  float sc[K*K];
  #pragma unroll
  for(int i = 0; i < K; ++i){
    #pragma unroll
    for(int j = 0; j < K; ++j){
      int ww = gy + D*(sy + j);
      float4 kv = *(const float4*)(kl + i*1024 + ww*16 + 4*t);
      float s = q.x*kv.x;
      s = fmaf(q.y, kv.y, s); s = fmaf(q.z, kv.z, s); s = fmaf(q.w, kv.w, s);
      sc[i*K + j] = s;
    }
  }
  float mx = -1e30f;
  #pragma unroll
  for(int i = 0; i < K; ++i){
    const float* brow = rpb + (head*RPB + (sx + i - px + (K-1)))*RPB + (sy - py + (K-1));
    #pragma unroll
    for(int j = 0; j < K; ++j){
      float s = sc[i*K + j];
      s += __shfl_xor(s, 1);
      s += __shfl_xor(s, 2);
      s += brow[j];
      sc[i*K + j] = s;
      mx = fmaxf(mx, s);
    }
  }
  float sum = 0.f;
  #pragma unroll
  for(int n = 0; n < K*K; ++n){ float e = __expf(sc[n] - mx); sc[n] = e; sum += e; }
  float rs = 1.0f / sum;
  float4 acc = {0,0,0,0};
  #pragma unroll
  for(int i = 0; i < K; ++i){
    #pragma unroll
    for(int j = 0; j < K; ++j){
      int ww = gy + D*(sy + j);
      float wgt = sc[i*K + j] * rs;
      float4 vv = *(const float4*)(vl + i*1024 + ww*16 + 4*t);
      acc.x = fmaf(wgt, vv.x, acc.x); acc.y = fmaf(wgt, vv.y, acc.y);
      acc.z = fmaf(wgt, vv.z, acc.z); acc.w = fmaf(wgt, vv.w, acc.w);
    }
  }
  __syncthreads();            // everyone done reading k-region
  float* ol = sm;             // 16 x 68 transpose buffer aliases k-region
  int r0 = 4*t;
  ol[(r0+0)*68 + pixoff] = acc.x;
  ol[(r0+1)*68 + pixoff] = acc.y;
  ol[(r0+2)*68 + pixoff] = acc.z;
  ol[(r0+3)*68 + pixoff] = acc.w;
  __syncthreads();
  int cb = b*CC + head*16;
  #pragma unroll
  for(int idx = tid; idx < 1024; idx += 256){
    int c = idx >> 6, p = idx & 63;
    outp[(cb + c)*NP + x*64 + p] = ol[c*68 + p];
  }
}

// ---- proj + residual + fused stats of result ----
__global__ void __launch_bounds__(256) gemm_proj_kernel(
    const float* __restrict__ att, const float* __restrict__ pw, const float* __restrict__ pb,
    const float* __restrict__ scx, const float* __restrict__ st,
    const float* __restrict__ m1w, const float* __restrict__ m1b,
    const float* __restrict__ m2w, const float* __restrict__ m2b,
    float* __restrict__ dst, float* __restrict__ st_out){
  int b = blockIdx.x >> 4, pix = (blockIdx.x & 15)*256 + threadIdx.x;
  int n0 = blockIdx.y * 8;
  const float* act = att + b*CC*NP + pix;
  float4 a0 = make_float4(0,0,0,0), a1 = a0;
  #pragma unroll 8
  for(int c = 0; c < CC; ++c){
    float a = act[c*NP];
    float4 w0 = *(const float4*)(pw + c*96 + n0);
    float4 w1 = *(const float4*)(pw + c*96 + n0 + 4);
    a0.x = fmaf(a, w0.x, a0.x); a0.y = fmaf(a, w0.y, a0.y);
    a0.z = fmaf(a, w0.z, a0.z); a0.w = fmaf(a, w0.w, a0.w);
    a1.x = fmaf(a, w1.x, a1.x); a1.y = fmaf(a, w1.y, a1.y);
    a1.z = fmaf(a, w1.z, a1.z); a1.w = fmaf(a, w1.w, a1.w);
  }
  float mean, inv, stdv; get_ms(st, b, mean, inv, stdv);
  float av[8] = {a0.x,a0.y,a0.z,a0.w,a1.x,a1.y,a1.z,a1.w};
  float s = 0.f, s2 = 0.f;
  #pragma unroll
  for(int cc = 0; cc < 8; ++cc){
    int c = n0 + cc;
    float rsf = fmaf(m1w[c], stdv, m1b[c]);
    float rbf = fmaf(m2w[c], mean, m2b[c]);
    int ad = (b*CC + c)*NP + pix;
    float val = scx[ad] + (av[cc] + pb[c])*rsf + rbf;
    dst[ad] = val;
    s += val; s2 = fmaf(val, val, s2);
  }
  for(int off = 32; off > 0; off >>= 1){ s += __shfl_down(s, off); s2 += __shfl_down(s2, off); }
  __shared__ float ls[8];
  int wid = threadIdx.x >> 6;
  if((threadIdx.x & 63) == 0){ ls[wid] = s; ls[4+wid] = s2; }
  __syncthreads();
  if(threadIdx.x == 0){
    atomicAdd(&st_out[b],   ls[0]+ls[1]+ls[2]+ls[3]);
    atomicAdd(&st_out[4+b], ls[4]+ls[5]+ls[6]+ls[7]);
  }
}

// ---- MLP layer 1 with fused LN: 32 outputs/thread ----
__global__ void __launch_bounds__(256) gemm_mlp1_kernel(
    const float* __restrict__ xin, const float* __restrict__ st,
    const float* __restrict__ lnw, const float* __restrict__ lnb,
    const float* __restrict__ w1t, const float* __restrict__ b1,
    float* __restrict__ hid){
  int b = blockIdx.x >> 4, pix = (blockIdx.x & 15)*256 + threadIdx.x;
  int n0 = blockIdx.y * 32;
  float mean, inv, stdv; get_ms(st, b, mean, inv, stdv);
  const float* act = xin + b*CC*NP + pix;
  float4 acc[8];
  #pragma unroll
  for(int j = 0; j < 8; ++j) acc[j] = make_float4(0,0,0,0);
  #pragma unroll 4
  for(int c = 0; c < CC; ++c){
    float s = inv * lnw[c];
    float o = lnb[c] - mean * s;
    float a = fmaf(act[c*NP], s, o);
    #pragma unroll
    for(int j = 0; j < 8; ++j){
      float4 wv = *(const float4*)(w1t + c*384 + n0 + j*4);
      acc[j].x = fmaf(a, wv.x, acc[j].x); acc[j].y = fmaf(a, wv.y, acc[j].y);
      acc[j].z = fmaf(a, wv.z, acc[j].z); acc[j].w = fmaf(a, wv.w, acc[j].w);
    }
  }
  const float* a = (const float*)acc;
  #pragma unroll
  for(int cc = 0; cc < 32; ++cc){
    int h = n0 + cc;
    hid[(b*384 + h)*NP + pix] = fmaxf(a[cc] + b1[h], 0.f);
  }
}

// ---- MLP layer 2 + residual (sc = x1): 16 outputs/thread ----
__global__ void __launch_bounds__(256) gemm_mlp2_kernel(
    const float* __restrict__ hid, const float* __restrict__ w2t, const float* __restrict__ b2,
    const float* __restrict__ scx, const float* __restrict__ st,
    const float* __restrict__ m1w, const float* __restrict__ m1b,
    const float* __restrict__ m2w, const float* __restrict__ m2b,
    float* __restrict__ dst){
  int b = blockIdx.x >> 4, pix = (blockIdx.x & 15)*256 + threadIdx.x;
  int n0 = blockIdx.y * 16;
  const float* act = hid + b*384*NP + pix;
  float4 acc[4];
  #pragma unroll
  for(int j = 0; j < 4; ++j) acc[j] = make_float4(0,0,0,0);
  #pragma unroll 8
  for(int c = 0; c < 384; ++c){
    float a = act[c*NP];
    #pragma unroll
    for(int j = 0; j < 4; ++j){
      float4 wv = *(const float4*)(w2t + c*96 + n0 + j*4);
      acc[j].x = fmaf(a, wv.x, acc[j].x); acc[j].y = fmaf(a, wv.y, acc[j].y);
      acc[j].z = fmaf(a, wv.z, acc[j].z); acc[j].w = fmaf(a, wv.w, acc[j].w);
    }
  }
  float mean, inv, stdv; get_ms(st, b, mean, inv, stdv);
  const float* a = (const float*)acc;
  #pragma unroll
  for(int cc = 0; cc < 16; ++cc){
    int c = n0 + cc;
    float rsf = fmaf(m1w[c], stdv, m1b[c]);
    float rbf = fmaf(m2w[c], mean, m2b[c]);
    int ad = (b*CC + c)*NP + pix;
    dst[ad] = scx[ad] + (a[cc] + b2[c])*rsf + rbf;
  }
}

// ---- pixel attention scalar map (BN fused) ----
__global__ void __launch_bounds__(64) pa_kernel(
    const float* __restrict__ x3, const float* __restrict__ bns,
    const float* __restrict__ w1t, const float* __restrict__ b1,
    const float* __restrict__ w2, const float* __restrict__ b2,
    float* __restrict__ pa){
  int pix = blockIdx.x*64 + threadIdx.x;
  int b = blockIdx.x >> 6;
  int p = pix & 4095;
  float acc[12];
  #pragma unroll
  for(int h = 0; h < 12; ++h) acc[h] = b1[h];
  #pragma unroll 4
  for(int c = 0; c < CC; ++c){
    float yv = fmaf(x3[(b*CC + c)*NP + p], bns[c], bns[96 + c]);
    #pragma unroll
    for(int h = 0; h < 12; ++h) acc[h] = fmaf(yv, w1t[c*12 + h], acc[h]);
  }
  float s = b2[0];
  #pragma unroll
  for(int h = 0; h < 12; ++h) s = fmaf(gelu_f(acc[h]), w2[h], s);
  pa[pix] = sigmoid_f(s);
}

// ---- global average pool of pa*ybn (BN fused) ----
__global__ void gap_kernel(const float* __restrict__ x3, const float* __restrict__ bns,
                           const float* __restrict__ pa, float* __restrict__ gap){
  int b = blockIdx.x / CC, c = blockIdx.x % CC;
  float scb = bns[c], shb = bns[96 + c];
  float s = 0.f;
  for(int i = threadIdx.x; i < NP; i += 256)
    s = fmaf(fmaf(x3[(b*CC + c)*NP + i], scb, shb), pa[b*NP + i], s);
  for(int off = 32; off > 0; off >>= 1) s += __shfl_down(s, off);
  __shared__ float ls[4];
  if((threadIdx.x & 63) == 0) ls[threadIdx.x >> 6] = s;
  __syncthreads();
  if(threadIdx.x == 0) gap[blockIdx.x] = (ls[0]+ls[1]+ls[2]+ls[3]) * (1.0f/4096.0f);
}

// ---- channel attention ----
__global__ void ca_kernel(const float* __restrict__ gap, const float* __restrict__ w1,
                          const float* __restrict__ b1, const float* __restrict__ w2,
                          const float* __restrict__ b2, float* __restrict__ ca){
  int b = blockIdx.x; int o = threadIdx.x;
  __shared__ float g[96], t[96];
  if(o < 96) g[o] = gap[b*96 + o];
  __syncthreads();
  if(o < 96){
    float a = b1[o];
    for(int c = 0; c < 96; ++c) a = fmaf(g[c], w1[o*96 + c], a);
    t[o] = gelu_f(a);
  }
  __syncthreads();
  if(o < 96){
    float a = b2[o];
    for(int c = 0; c < 96; ++c) a = fmaf(t[c], w2[o*96 + c], a);
    ca[b*96 + o] = sigmoid_f(a);
  }
}

// ---- m2a layer 1: BN + ca*pa fused, gelu epilogue, 16 outputs ----
__global__ void __launch_bounds__(256) gemm_m2a1_kernel(
    const float* __restrict__ x3, const float* __restrict__ bns,
    const float* __restrict__ pa, const float* __restrict__ ca,
    const float* __restrict__ w1t, const float* __restrict__ b1,
    float* __restrict__ tb){
  int b = blockIdx.x >> 4, pix = (blockIdx.x & 15)*256 + threadIdx.x;
  int n0 = blockIdx.y * 16;
  const float* act = x3 + b*CC*NP + pix;
  const float* cac = ca + b*CC;
  float pav = pa[b*NP + pix];
  float4 acc[4];
  #pragma unroll
  for(int j = 0; j < 4; ++j) acc[j] = make_float4(0,0,0,0);
  #pragma unroll 4
  for(int c = 0; c < CC; ++c){
    float g = cac[c] * pav;
    float a = fmaf(act[c*NP], bns[c], bns[96 + c]) * g;
    #pragma unroll
    for(int j = 0; j < 4; ++j){
      float4 wv = *(const float4*)(w1t + c*96 + n0 + j*4);
      acc[j].x = fmaf(a, wv.x, acc[j].x); acc[j].y = fmaf(a, wv.y, acc[j].y);
      acc[j].z = fmaf(a, wv.z, acc[j].z); acc[j].w = fmaf(a, wv.w, acc[j].w);
    }
  }
  const float* a = (const float*)acc;
  #pragma unroll
  for(int cc = 0; cc < 16; ++cc){
    int c = n0 + cc;
    tb[(b*CC + c)*NP + pix] = gelu_f(a[cc] + b1[c]);
  }
}

// ---- m2a layer 2 + final residual: 16 outputs ----
__global__ void __launch_bounds__(256) gemm_m2a2_kernel(
    const float* __restrict__ tb, const float* __restrict__ w2t, const float* __restrict__ b2,
    const float* __restrict__ scx, float* __restrict__ outp){
  int b = blockIdx.x >> 4, pix = (blockIdx.x & 15)*256 + threadIdx.x;
  int n0 = blockIdx.y * 16;
  const float* act = tb + b*CC*NP + pix;
  float4 acc[4];
  #pragma unroll
  for(int j = 0; j < 4; ++j) acc[j] = make_float4(0,0,0,0);
  #pragma unroll 8
  for(int c = 0; c < CC; ++c){
    float a = act[c*NP];
    #pragma unroll
    for(int j = 0; j < 4; ++j){
      float4 wv = *(const float4*)(w2t + c*96 + n0 + j*4);
      acc[j].x = fmaf(a, wv.x, acc[j].x); acc[j].y = fmaf(a, wv.y, acc[j].y);
      acc[j].z = fmaf(a, wv.z, acc[j].z); acc[j].w = fmaf(a, wv.w, acc[j].w);
    }
  }
  const float* a = (const float*)acc;
  #pragma unroll
  for(int cc = 0; cc < 16; ++cc){
    int c = n0 + cc;
    int ad = (b*CC + c)*NP + pix;
    outp[ad] = scx[ad] + a[cc] + b2[c];
  }
}

extern "C" void kernel_launch(void* const* d_in, const int* in_sizes, int n_in,
                              void* d_out, int out_size, void* d_ws, size_t ws_size,
                              hipStream_t stream){
  (void)in_sizes; (void)n_in; (void)out_size; (void)ws_size;
  const float* x     = (const float*)d_in[0];
  const float* lnw   = (const float*)d_in[1];
  const float* lnb   = (const float*)d_in[2];
  const float* m1w   = (const float*)d_in[3];
  const float* m1b   = (const float*)d_in[4];
  const float* m2w   = (const float*)d_in[5];
  const float* m2b   = (const float*)d_in[6];
  const float* qkv1w = (const float*)d_in[7];
  const float* qkv1b = (const float*)d_in[8];
  const float* proj1w= (const float*)d_in[9];
  const float* proj1b= (const float*)d_in[10];
  const float* rpb1  = (const float*)d_in[11];
  const float* qkv2w = (const float*)d_in[12];
  const float* qkv2b = (const float*)d_in[13];
  const float* proj2w= (const float*)d_in[14];
  const float* proj2b= (const float*)d_in[15];
  const float* rpb2  = (const float*)d_in[16];
  const float* mw1   = (const float*)d_in[17];
  const float* mb1   = (const float*)d_in[18];
  const float* mw2   = (const float*)d_in[19];
  const float* mb2   = (const float*)d_in[20];
  const float* bng   = (const float*)d_in[21];
  const float* bnb   = (const float*)d_in[22];
  const float* bnm   = (const float*)d_in[23];
  const float* bnv   = (const float*)d_in[24];
  const float* paw1  = (const float*)d_in[25];
  const float* pab1  = (const float*)d_in[26];
  const float* paw2  = (const float*)d_in[27];
  const float* pab2  = (const float*)d_in[28];
  const float* caw1  = (const float*)d_in[29];
  const float* cab1  = (const float*)d_in[30];
  const float* caw2  = (const float*)d_in[31];
  const float* cab2  = (const float*)d_in[32];
  const float* aw1   = (const float*)d_in[33];
  const float* ab1   = (const float*)d_in[34];
  const float* aw2   = (const float*)d_in[35];
  const float* ab2   = (const float*)d_in[36];

  float* ws  = (float*)d_ws;
  float* out = (float*)d_out;
  float* st0 = ws + WS_STATS;
  float* st1 = st0 + 8;
  float* st2 = st0 + 16;
  float* q   = ws + WS_Q;
  float* k   = ws + WS_K;
  float* v   = ws + WS_V;
  float* att = ws + WS_ATT;
  float* hid = ws + WS_Q;
  float* x1  = ws + WS_X1;
  float* x2  = ws + WS_X2;
  float* x3  = ws + WS_X3;
  float* pab = ws + WS_PAB;
  float* gpb = ws + WS_GAP;
  float* cab = ws + WS_CA;
  float* tbf = ws + WS_K;
  float* bns = ws + WS_BNS;

  hipMemsetAsync(d_ws, 0, 64*sizeof(float), stream);
  prep_weights<<<365, 256, 0, stream>>>(mw1, mw2, aw1, aw2, paw1, bng, bnb, bnm, bnv, ws);

  // stage 1: attn k=7 d=1
  stats_kernel<<<384, 256, 0, stream>>>(x, st0);
  gemm_qkv_kernel<<<dim3(64,9), 256, 0, stream>>>(x, st0, lnw, lnb, qkv1w, qkv1b, q, k, v);
  attn_kernel<7,1,13><<<1536, 256, 0, stream>>>(q, k, v, rpb1, att);
  gemm_proj_kernel<<<dim3(64,12), 256, 0, stream>>>(att, proj1w, proj1b, x, st0, m1w, m1b, m2w, m2b, x1, st1);

  // stage 2: attn k=5 d=8
  gemm_qkv_kernel<<<dim3(64,9), 256, 0, stream>>>(x1, st1, lnw, lnb, qkv2w, qkv2b, q, k, v);
  attn_kernel<5,8,9><<<1536, 256, 0, stream>>>(q, k, v, rpb2, att);
  gemm_proj_kernel<<<dim3(64,12), 256, 0, stream>>>(att, proj2w, proj2b, x1, st1, m1w, m1b, m2w, m2b, x2, st2);

  // stage 3: MLP (sc = x1 per reference)
  gemm_mlp1_kernel<<<dim3(64,12), 256, 0, stream>>>(x2, st2, lnw, lnb, ws + WS_W1T, mb1, hid);
  gemm_mlp2_kernel<<<dim3(64,6), 256, 0, stream>>>(hid, ws + WS_W2T, mb2, x1, st2, m1w, m1b, m2w, m2b, x3);

  // stage 4: BN(fused) + pixel/channel attention + m2a + final residual (sc = x3)
  pa_kernel<<<256, 64, 0, stream>>>(x3, bns, ws + WS_PA1T, pab1, paw2, pab2, pab);
  gap_kernel<<<384, 256, 0, stream>>>(x3, bns, pab, gpb);
  ca_kernel<<<4, 128, 0, stream>>>(gpb, caw1, cab1, caw2, cab2, cab);
  gemm_m2a1_kernel<<<dim3(64,6), 256, 0, stream>>>(x3, bns, pab, cab, ws + WS_M2A1T, ab1, tbf);
  gemm_m2a2_kernel<<<dim3(64,6), 256, 0, stream>>>(tbf, ws + WS_M2A2T, ab2, x3, out);
}

// Round 5
// 307.295 us; speedup vs baseline: 1.5283x; 1.5283x over previous
//
#include <hip/hip_runtime.h>
#include <math.h>

#define CC 96
#define NP 4096
#define NHEADS 6
#define NELEMF 393216.0f
#define EPSF 1e-5f

typedef __attribute__((ext_vector_type(8))) short bf16x8;
typedef __attribute__((ext_vector_type(4))) float f32x4;
#define MFMA16(a,b,c) __builtin_amdgcn_mfma_f32_16x16x32_bf16(a,b,c,0,0,0)

// ---- workspace layout (float offsets) ----
#define WS_STATS 0
#define WQKV1  64
#define WQKV2  (WQKV1+13824)
#define WPROJ1 (WQKV2+13824)
#define WPROJ2 (WPROJ1+4608)
#define WMLP1  (WPROJ2+4608)
#define WMLP2  (WMLP1+18432)
#define WM2A1  (WMLP2+18432)
#define WM2A2  (WM2A1+4608)
#define WPA1T  (WM2A2+4608)
#define WBNS   (WPA1T+1152)
#define WS_YPM 84352
#define WS_Q   870784
#define WS_K   (WS_Q+1572864)
#define WS_V   (WS_K+1572864)
#define WS_ATTPM (WS_V+1572864)
#define WS_X1  (WS_ATTPM+786432)
#define WS_X2  (WS_X1+1572864)
#define WS_X3  (WS_X2+1572864)
#define WS_PA  (WS_X3+1572864)
#define WS_GAP (WS_PA+16384)
#define WS_CA  (WS_GAP+384)

__device__ __forceinline__ float gelu_f(float x){
  return 0.5f * x * (1.0f + erff(x * 0.7071067811865476f));
}
__device__ __forceinline__ float sigmoid_f(float x){
  return 1.0f / (1.0f + __expf(-x));
}
__device__ __forceinline__ unsigned short bfr(float f){
  unsigned int u = __float_as_uint(f);
  u += 0x7fffu + ((u >> 16) & 1u);
  return (unsigned short)(u >> 16);
}
__device__ __forceinline__ unsigned int bfpack(float a, float b){
  return (unsigned int)bfr(a) | ((unsigned int)bfr(b) << 16);
}
__device__ __forceinline__ void get_ms(const float* st, int b, float& mean, float& inv, float& stdv){
  float s = st[b], s2 = st[4+b];
  mean = s * (1.0f/NELEMF);
  float var = fmaxf(s2 * (1.0f/NELEMF) - mean*mean, 0.0f);
  stdv = sqrtf(var + EPSF);
  inv = 1.0f / stdv;
}

// ---- per-batch sum/sumsq over input x ----
__global__ void stats_kernel(const float* __restrict__ src, float* __restrict__ st){
  int b = blockIdx.x / CC, c = blockIdx.x % CC;
  const float* p = src + (b*CC + c)*NP;
  float s = 0.f, s2 = 0.f;
  for(int i = threadIdx.x; i < NP; i += 256){ float v = p[i]; s += v; s2 = fmaf(v, v, s2); }
  for(int off = 32; off > 0; off >>= 1){ s += __shfl_down(s, off); s2 += __shfl_down(s2, off); }
  __shared__ float ls[8];
  int wid = threadIdx.x >> 6;
  if((threadIdx.x & 63) == 0){ ls[wid] = s; ls[4+wid] = s2; }
  __syncthreads();
  if(threadIdx.x == 0){
    atomicAdd(&st[b],   ls[0]+ls[1]+ls[2]+ls[3]);
    atomicAdd(&st[4+b], ls[4]+ls[5]+ls[6]+ls[7]);
  }
}

// ---- convert all weights to bf16 W^T[n][k]; BN scale/shift; pa1 transpose ----
__global__ void prep_weights(const float* __restrict__ q1, const float* __restrict__ q2,
                             const float* __restrict__ p1, const float* __restrict__ p2,
                             const float* __restrict__ w1, const float* __restrict__ w2,
                             const float* __restrict__ a1, const float* __restrict__ a2,
                             const float* __restrict__ pw1,
                             const float* __restrict__ bg, const float* __restrict__ bb,
                             const float* __restrict__ bm, const float* __restrict__ bv,
                             float* __restrict__ ws){
  int gid = blockIdx.x*256 + threadIdx.x;
  if(gid < 27648){ int n = gid/96, c = gid%96; ((unsigned short*)(ws+WQKV1))[gid] = bfr(q1[c*288+n]); }
  else if(gid < 55296){ int g = gid-27648; int n = g/96, c = g%96; ((unsigned short*)(ws+WQKV2))[g] = bfr(q2[c*288+n]); }
  else if(gid < 64512){ int g = gid-55296; int n = g/96, c = g%96; ((unsigned short*)(ws+WPROJ1))[g] = bfr(p1[c*96+n]); }
  else if(gid < 73728){ int g = gid-64512; int n = g/96, c = g%96; ((unsigned short*)(ws+WPROJ2))[g] = bfr(p2[c*96+n]); }
  else if(gid < 110592){ int g = gid-73728; ((unsigned short*)(ws+WMLP1))[g] = bfr(w1[g]); }
  else if(gid < 147456){ int g = gid-110592; ((unsigned short*)(ws+WMLP2))[g] = bfr(w2[g]); }
  else if(gid < 156672){ int g = gid-147456; ((unsigned short*)(ws+WM2A1))[g] = bfr(a1[g]); }
  else if(gid < 165888){ int g = gid-156672; ((unsigned short*)(ws+WM2A2))[g] = bfr(a2[g]); }
  else if(gid < 167040){ int g = gid-165888; int c = g/12, h = g%12; ws[WPA1T + g] = pw1[h*96+c]; }
  else if(gid < 167136){ int c = gid-167040;
    float sc = rsqrtf(bv[c] + EPSF) * bg[c];
    ws[WBNS + c] = sc;
    ws[WBNS + 96 + c] = bb[c] - bm[c]*sc;
  }
}

// ---- LN + transpose to pixel-major bf16: y[16384][96] ----
__global__ void __launch_bounds__(256) ln_tr_kernel(
    const float* __restrict__ src, const float* __restrict__ st,
    const float* __restrict__ lnw, const float* __restrict__ lnb,
    unsigned int* __restrict__ dst){   // dst viewed as dwords (2 bf16 each), 48 per row
  int px0 = blockIdx.x*64; int b = px0 >> 12; int pxl0 = px0 & 4095;
  float mean, inv, stdv; get_ms(st, b, mean, inv, stdv);
  __shared__ float T[96*67];
  for(int idx = threadIdx.x; idx < 96*64; idx += 256){
    int c = idx >> 6, p = idx & 63;
    float s = inv*lnw[c]; float o = lnb[c] - mean*s;
    T[c*67 + p] = fmaf(src[(b*96 + c)*NP + pxl0 + p], s, o);
  }
  __syncthreads();
  for(int idx = threadIdx.x; idx < 64*48; idx += 256){
    int row = idx/48, cd = idx%48;
    dst[(px0 + row)*48 + cd] = bfpack(T[(2*cd)*67 + row], T[(2*cd+1)*67 + row]);
  }
}

// ---- BN*pa*ca + transpose to pixel-major bf16 (stage 4 m2a input) ----
__global__ void __launch_bounds__(256) y3_tr_kernel(
    const float* __restrict__ x3, const float* __restrict__ bns,
    const float* __restrict__ pa, const float* __restrict__ ca,
    unsigned int* __restrict__ dst){
  int px0 = blockIdx.x*64; int b = px0 >> 12; int pxl0 = px0 & 4095;
  __shared__ float T[96*67];
  for(int idx = threadIdx.x; idx < 96*64; idx += 256){
    int c = idx >> 6, p = idx & 63;
    float v = fmaf(x3[(b*96 + c)*NP + pxl0 + p], bns[c], bns[96 + c]);
    T[c*67 + p] = v * ca[b*96 + c] * pa[px0 + p];
  }
  __syncthreads();
  for(int idx = threadIdx.x; idx < 64*48; idx += 256){
    int row = idx/48, cd = idx%48;
    dst[(px0 + row)*48 + cd] = bfpack(T[(2*cd)*67 + row], T[(2*cd+1)*67 + row]);
  }
}

// ---- MFMA core: wave computes 32px x 48n, K-loop ----
template<int K>
__device__ __forceinline__ void mfma_tile(const unsigned short* __restrict__ A,
                                          const unsigned short* __restrict__ W,
                                          int m_base, int n_base, f32x4 acc[2][3]){
  int lane = threadIdx.x & 63;
  int ml = lane & 15, q = lane >> 4;
  const bf16x8* a0 = (const bf16x8*)(A + (size_t)(m_base + ml)*K + q*8);
  const bf16x8* a1 = (const bf16x8*)(A + (size_t)(m_base + 16 + ml)*K + q*8);
  const bf16x8* b0 = (const bf16x8*)(W + (n_base + ml)*K + q*8);
  const bf16x8* b1 = (const bf16x8*)(W + (n_base + 16 + ml)*K + q*8);
  const bf16x8* b2 = (const bf16x8*)(W + (n_base + 32 + ml)*K + q*8);
  #pragma unroll
  for(int ks = 0; ks < K/32; ++ks){
    bf16x8 av0 = a0[ks*4], av1 = a1[ks*4];
    bf16x8 bv0 = b0[ks*4], bv1 = b1[ks*4], bv2 = b2[ks*4];
    acc[0][0] = MFMA16(av0, bv0, acc[0][0]);
    acc[0][1] = MFMA16(av0, bv1, acc[0][1]);
    acc[0][2] = MFMA16(av0, bv2, acc[0][2]);
    acc[1][0] = MFMA16(av1, bv0, acc[1][0]);
    acc[1][1] = MFMA16(av1, bv1, acc[1][1]);
    acc[1][2] = MFMA16(av1, bv2, acc[1][2]);
  }
}

// ---- QKV GEMM: ypm[16384][96] @ WqkvT[288][96] -> q/k/v fp32 [b,head,px,16] ----
__global__ void __launch_bounds__(256) gemm_qkv_kernel(
    const unsigned short* __restrict__ ypm, const unsigned short* __restrict__ wT,
    const float* __restrict__ qb,
    float* __restrict__ qo, float* __restrict__ ko, float* __restrict__ vo){
  int w = threadIdx.x >> 6, lane = threadIdx.x & 63;
  int ml = lane & 15, q = lane >> 4;
  int m_base = blockIdx.x*128 + w*32;
  int n0 = blockIdx.y*48;
  f32x4 acc[2][3];
  f32x4 z = {0.f,0.f,0.f,0.f};
  #pragma unroll
  for(int f=0; f<2; ++f) for(int g=0; g<3; ++g) acc[f][g] = z;
  mfma_tile<96>(ypm, wT, m_base, n0, acc);
  #pragma unroll
  for(int g = 0; g < 3; ++g){
    int nfb = n0 + g*16;
    int t = nfb/96, head = (nfb%96) >> 4;
    float scale = (t == 0) ? 0.25f : 1.0f;
    float* dst = (t == 0) ? qo : (t == 1) ? ko : vo;
    float bias = qb[nfb + ml];
    #pragma unroll
    for(int f = 0; f < 2; ++f){
      #pragma unroll
      for(int r = 0; r < 4; ++r){
        int m = m_base + f*16 + q*4 + r;
        int b = m >> 12, pxl = m & 4095;
        dst[(((size_t)(b*NHEADS + head))*NP + pxl)*16 + ml] = (acc[f][g][r] + bias)*scale;
      }
    }
  }
}

// ---- proj GEMM: attpm @ projT -> c-major + residual + fused stats ----
__global__ void __launch_bounds__(256) gemm_proj_kernel(
    const unsigned short* __restrict__ attpm, const unsigned short* __restrict__ wT,
    const float* __restrict__ pb, const float* __restrict__ scx, const float* __restrict__ st,
    const float* __restrict__ m1w, const float* __restrict__ m1b,
    const float* __restrict__ m2w, const float* __restrict__ m2b,
    float* __restrict__ dst, float* __restrict__ st_out){
  int w = threadIdx.x >> 6, lane = threadIdx.x & 63;
  int ml = lane & 15, q = lane >> 4;
  int m_base = blockIdx.x*128 + w*32;
  int n0 = blockIdx.y*48;
  f32x4 acc[2][3];
  f32x4 z = {0.f,0.f,0.f,0.f};
  #pragma unroll
  for(int f=0; f<2; ++f) for(int g=0; g<3; ++g) acc[f][g] = z;
  mfma_tile<96>(attpm, wT, m_base, n0, acc);
  __shared__ float T[48*133];
  #pragma unroll
  for(int f = 0; f < 2; ++f)
    #pragma unroll
    for(int g = 0; g < 3; ++g)
      #pragma unroll
      for(int r = 0; r < 4; ++r)
        T[(g*16 + ml)*133 + w*32 + f*16 + q*4 + r] = acc[f][g][r];
  __syncthreads();
  int b = (blockIdx.x*128) >> 12, pxl0 = (blockIdx.x*128) & 4095;
  float mean, inv, stdv; get_ms(st, b, mean, inv, stdv);
  float s = 0.f, s2 = 0.f;
  for(int idx = threadIdx.x; idx < 48*128; idx += 256){
    int row = idx >> 7, px = idx & 127;
    int n = n0 + row;
    float rsf = fmaf(m1w[n], stdv, m1b[n]);
    float rbf = fmaf(m2w[n], mean, m2b[n]);
    int ad = (b*CC + n)*NP + pxl0 + px;
    float val = scx[ad] + (T[row*133 + px] + pb[n])*rsf + rbf;
    dst[ad] = val;
    s += val; s2 = fmaf(val, val, s2);
  }
  for(int off = 32; off > 0; off >>= 1){ s += __shfl_down(s, off); s2 += __shfl_down(s2, off); }
  __shared__ float ls[8];
  int wid = threadIdx.x >> 6;
  if((threadIdx.x & 63) == 0){ ls[wid] = s; ls[4+wid] = s2; }
  __syncthreads();
  if(threadIdx.x == 0){
    atomicAdd(&st_out[b],   ls[0]+ls[1]+ls[2]+ls[3]);
    atomicAdd(&st_out[4+b], ls[4]+ls[5]+ls[6]+ls[7]);
  }
}

// ---- mlp1 GEMM: ypm @ mlp1T -> relu -> hid pixel-major bf16 [16384][384] ----
__global__ void __launch_bounds__(256) gemm_mlp1_kernel(
    const unsigned short* __restrict__ ypm, const unsigned short* __restrict__ wT,
    const float* __restrict__ b1, unsigned short* __restrict__ hid){
  int w = threadIdx.x >> 6, lane = threadIdx.x & 63;
  int ml = lane & 15, q = lane >> 4;
  int m_base = blockIdx.x*128 + w*32;
  int n0 = blockIdx.y*48;
  f32x4 acc[2][3];
  f32x4 z = {0.f,0.f,0.f,0.f};
  #pragma unroll
  for(int f=0; f<2; ++f) for(int g=0; g<3; ++g) acc[f][g] = z;
  mfma_tile<96>(ypm, wT, m_base, n0, acc);
  #pragma unroll
  for(int g = 0; g < 3; ++g){
    int n = n0 + g*16 + ml;
    float bias = b1[n];
    #pragma unroll
    for(int f = 0; f < 2; ++f)
      #pragma unroll
      for(int r = 0; r < 4; ++r){
        int m = m_base + f*16 + q*4 + r;
        hid[(size_t)m*384 + n] = bfr(fmaxf(acc[f][g][r] + bias, 0.f));
      }
  }
}

// ---- mlp2 GEMM (K=384): hid @ mlp2T -> c-major + residual(x1) via st2 ----
__global__ void __launch_bounds__(256) gemm_mlp2_kernel(
    const unsigned short* __restrict__ hid, const unsigned short* __restrict__ wT,
    const float* __restrict__ b2, const float* __restrict__ scx, const float* __restrict__ st,
    const float* __restrict__ m1w, const float* __restrict__ m1b,
    const float* __restrict__ m2w, const float* __restrict__ m2b,
    float* __restrict__ dst){
  int w = threadIdx.x >> 6, lane = threadIdx.x & 63;
  int ml = lane & 15, q = lane >> 4;
  int m_base = blockIdx.x*128 + w*32;
  int n0 = blockIdx.y*48;
  f32x4 acc[2][3];
  f32x4 z = {0.f,0.f,0.f,0.f};
  #pragma unroll
  for(int f=0; f<2; ++f) for(int g=0; g<3; ++g) acc[f][g] = z;
  mfma_tile<384>(hid, wT, m_base, n0, acc);
  __shared__ float T[48*133];
  #pragma unroll
  for(int f = 0; f < 2; ++f)
    #pragma unroll
    for(int g = 0; g < 3; ++g)
      #pragma unroll
      for(int r = 0; r < 4; ++r)
        T[(g*16 + ml)*133 + w*32 + f*16 + q*4 + r] = acc[f][g][r];
  __syncthreads();
  int b = (blockIdx.x*128) >> 12, pxl0 = (blockIdx.x*128) & 4095;
  float mean, inv, stdv; get_ms(st, b, mean, inv, stdv);
  for(int idx = threadIdx.x; idx < 48*128; idx += 256){
    int row = idx >> 7, px = idx & 127;
    int n = n0 + row;
    float rsf = fmaf(m1w[n], stdv, m1b[n]);
    float rbf = fmaf(m2w[n], mean, m2b[n]);
    int ad = (b*CC + n)*NP + pxl0 + px;
    dst[ad] = scx[ad] + (T[row*133 + px] + b2[n])*rsf + rbf;
  }
}

// ---- m2a1 GEMM: y3pm @ m2a1T -> gelu -> tpm pixel-major bf16 ----
__global__ void __launch_bounds__(256) gemm_m2a1_kernel(
    const unsigned short* __restrict__ y3pm, const unsigned short* __restrict__ wT,
    const float* __restrict__ b1, unsigned short* __restrict__ tpm){
  int w = threadIdx.x >> 6, lane = threadIdx.x & 63;
  int ml = lane & 15, q = lane >> 4;
  int m_base = blockIdx.x*128 + w*32;
  int n0 = blockIdx.y*48;
  f32x4 acc[2][3];
  f32x4 z = {0.f,0.f,0.f,0.f};
  #pragma unroll
  for(int f=0; f<2; ++f) for(int g=0; g<3; ++g) acc[f][g] = z;
  mfma_tile<96>(y3pm, wT, m_base, n0, acc);
  #pragma unroll
  for(int g = 0; g < 3; ++g){
    int n = n0 + g*16 + ml;
    float bias = b1[n];
    #pragma unroll
    for(int f = 0; f < 2; ++f)
      #pragma unroll
      for(int r = 0; r < 4; ++r){
        int m = m_base + f*16 + q*4 + r;
        tpm[(size_t)m*96 + n] = bfr(gelu_f(acc[f][g][r] + bias));
      }
  }
}

// ---- m2a2 GEMM: tpm @ m2a2T -> c-major + final residual(x3) -> out ----
__global__ void __launch_bounds__(256) gemm_m2a2_kernel(
    const unsigned short* __restrict__ tpm, const unsigned short* __restrict__ wT,
    const float* __restrict__ b2, const float* __restrict__ scx, float* __restrict__ outp){
  int w = threadIdx.x >> 6, lane = threadIdx.x & 63;
  int ml = lane & 15, q = lane >> 4;
  int m_base = blockIdx.x*128 + w*32;
  int n0 = blockIdx.y*48;
  f32x4 acc[2][3];
  f32x4 z = {0.f,0.f,0.f,0.f};
  #pragma unroll
  for(int f=0; f<2; ++f) for(int g=0; g<3; ++g) acc[f][g] = z;
  mfma_tile<96>(tpm, wT, m_base, n0, acc);
  __shared__ float T[48*133];
  #pragma unroll
  for(int f = 0; f < 2; ++f)
    #pragma unroll
    for(int g = 0; g < 3; ++g)
      #pragma unroll
      for(int r = 0; r < 4; ++r)
        T[(g*16 + ml)*133 + w*32 + f*16 + q*4 + r] = acc[f][g][r];
  __syncthreads();
  int b = (blockIdx.x*128) >> 12, pxl0 = (blockIdx.x*128) & 4095;
  for(int idx = threadIdx.x; idx < 48*128; idx += 256){
    int row = idx >> 7, px = idx & 127;
    int n = n0 + row;
    int ad = (b*CC + n)*NP + pxl0 + px;
    outp[ad] = scx[ad] + T[row*133 + px] + b2[n];
  }
}

// ---- neighborhood attention: LDS-staged k/v, output pixel-major bf16 ----
template<int K, int D, int RPB>
__global__ void __launch_bounds__(256) attn_kernel(
    const float* __restrict__ qb, const float* __restrict__ kb,
    const float* __restrict__ vb, const float* __restrict__ rpb,
    unsigned short* __restrict__ outp){
  int bh = blockIdx.x >> 6;
  int x = blockIdx.x & 63;
  int head = bh % NHEADS, b = bh / NHEADS;

  int gx = x % D, px = x / D;
  int Lgx = (64 - gx + D - 1) / D;
  int sx = min(max(px - K/2, 0), Lgx - K);

  __shared__ float sm[2*K*1024];
  float* kl = sm;
  float* vl = sm + K*1024;
  const float* kg = kb + (size_t)bh*NP*16;
  const float* vg = vb + (size_t)bh*NP*16;
  int tid = threadIdx.x;
  #pragma unroll
  for(int i = 0; i < K; ++i){
    int hh = gx + D*(sx + i);
    ((float4*)(kl + i*1024))[tid] = ((const float4*)(kg + hh*1024))[tid];
    ((float4*)(vl + i*1024))[tid] = ((const float4*)(vg + hh*1024))[tid];
  }
  __syncthreads();

  int pixoff = tid >> 2, t = tid & 3;
  int y = pixoff;
  int pix = x*64 + y;
  const float4 q = *(const float4*)(qb + ((size_t)bh*NP + pix)*16 + 4*t);

  int gy = y % D, py = y / D;
  int Lgy = (64 - gy + D - 1) / D;
  int sy = min(max(py - K/2, 0), Lgy - K);

  float sc[K*K];
  #pragma unroll
  for(int i = 0; i < K; ++i){
    #pragma unroll
    for(int j = 0; j < K; ++j){
      int ww = gy + D*(sy + j);
      float4 kv = *(const float4*)(kl + i*1024 + ww*16 + 4*t);
      float s = q.x*kv.x;
      s = fmaf(q.y, kv.y, s); s = fmaf(q.z, kv.z, s); s = fmaf(q.w, kv.w, s);
      sc[i*K + j] = s;
    }
  }
  float mx = -1e30f;
  #pragma unroll
  for(int i = 0; i < K; ++i){
    const float* brow = rpb + (head*RPB + (sx + i - px + (K-1)))*RPB + (sy - py + (K-1));
    #pragma unroll
    for(int j = 0; j < K; ++j){
      float s = sc[i*K + j];
      s += __shfl_xor(s, 1);
      s += __shfl_xor(s, 2);
      s += brow[j];
      sc[i*K + j] = s;
      mx = fmaxf(mx, s);
    }
  }
  float sum = 0.f;
  #pragma unroll
  for(int n = 0; n < K*K; ++n){ float e = __expf(sc[n] - mx); sc[n] = e; sum += e; }
  float rs = 1.0f / sum;
  float4 acc = {0,0,0,0};
  #pragma unroll
  for(int i = 0; i < K; ++i){
    #pragma unroll
    for(int j = 0; j < K; ++j){
      int ww = gy + D*(sy + j);
      float wgt = sc[i*K + j] * rs;
      float4 vv = *(const float4*)(vl + i*1024 + ww*16 + 4*t);
      acc.x = fmaf(wgt, vv.x, acc.x); acc.y = fmaf(wgt, vv.y, acc.y);
      acc.z = fmaf(wgt, vv.z, acc.z); acc.w = fmaf(wgt, vv.w, acc.w);
    }
  }
  ushort4 o4;
  o4.x = bfr(acc.x); o4.y = bfr(acc.y); o4.z = bfr(acc.z); o4.w = bfr(acc.w);
  *(ushort4*)(outp + ((size_t)(b*NP + pix))*96 + head*16 + 4*t) = o4;
}

// ---- pixel attention scalar map (BN fused, x3 c-major) ----
__global__ void __launch_bounds__(64) pa_kernel(
    const float* __restrict__ x3, const float* __restrict__ bns,
    const float* __restrict__ w1t, const float* __restrict__ b1,
    const float* __restrict__ w2, const float* __restrict__ b2,
    float* __restrict__ pa){
  int pix = blockIdx.x*64 + threadIdx.x;
  int b = blockIdx.x >> 6;
  int p = pix & 4095;
  float acc[12];
  #pragma unroll
  for(int h = 0; h < 12; ++h) acc[h] = b1[h];
  #pragma unroll 4
  for(int c = 0; c < CC; ++c){
    float yv = fmaf(x3[(b*CC + c)*NP + p], bns[c], bns[96 + c]);
    #pragma unroll
    for(int h = 0; h < 12; ++h) acc[h] = fmaf(yv, w1t[c*12 + h], acc[h]);
  }
  float s = b2[0];
  #pragma unroll
  for(int h = 0; h < 12; ++h) s = fmaf(gelu_f(acc[h]), w2[h], s);
  pa[pix] = sigmoid_f(s);
}

// ---- global average pool of pa*BN(x3) ----
__global__ void gap_kernel(const float* __restrict__ x3, const float* __restrict__ bns,
                           const float* __restrict__ pa, float* __restrict__ gap){
  int b = blockIdx.x / CC, c = blockIdx.x % CC;
  float scb = bns[c], shb = bns[96 + c];
  float s = 0.f;
  for(int i = threadIdx.x; i < NP; i += 256)
    s = fmaf(fmaf(x3[(b*CC + c)*NP + i], scb, shb), pa[b*NP + i], s);
  for(int off = 32; off > 0; off >>= 1) s += __shfl_down(s, off);
  __shared__ float ls[4];
  if((threadIdx.x & 63) == 0) ls[threadIdx.x >> 6] = s;
  __syncthreads();
  if(threadIdx.x == 0) gap[blockIdx.x] = (ls[0]+ls[1]+ls[2]+ls[3]) * (1.0f/4096.0f);
}

// ---- channel attention ----
__global__ void ca_kernel(const float* __restrict__ gap, const float* __restrict__ w1,
                          const float* __restrict__ b1, const float* __restrict__ w2,
                          const float* __restrict__ b2, float* __restrict__ ca){
  int b = blockIdx.x; int o = threadIdx.x;
  __shared__ float g[96], t[96];
  if(o < 96) g[o] = gap[b*96 + o];
  __syncthreads();
  if(o < 96){
    float a = b1[o];
    for(int c = 0; c < 96; ++c) a = fmaf(g[c], w1[o*96 + c], a);
    t[o] = gelu_f(a);
  }
  __syncthreads();
  if(o < 96){
    float a = b2[o];
    for(int c = 0; c < 96; ++c) a = fmaf(t[c], w2[o*96 + c], a);
    ca[b*96 + o] = sigmoid_f(a);
  }
}

extern "C" void kernel_launch(void* const* d_in, const int* in_sizes, int n_in,
                              void* d_out, int out_size, void* d_ws, size_t ws_size,
                              hipStream_t stream){
  (void)in_sizes; (void)n_in; (void)out_size; (void)ws_size;
  const float* x     = (const float*)d_in[0];
  const float* lnw   = (const float*)d_in[1];
  const float* lnb   = (const float*)d_in[2];
  const float* m1w   = (const float*)d_in[3];
  const float* m1b   = (const float*)d_in[4];
  const float* m2w   = (const float*)d_in[5];
  const float* m2b   = (const float*)d_in[6];
  const float* qkv1w = (const float*)d_in[7];
  const float* qkv1b = (const float*)d_in[8];
  const float* proj1w= (const float*)d_in[9];
  const float* proj1b= (const float*)d_in[10];
  const float* rpb1  = (const float*)d_in[11];
  const float* qkv2w = (const float*)d_in[12];
  const float* qkv2b = (const float*)d_in[13];
  const float* proj2w= (const float*)d_in[14];
  const float* proj2b= (const float*)d_in[15];
  const float* rpb2  = (const float*)d_in[16];
  const float* mw1   = (const float*)d_in[17];
  const float* mb1   = (const float*)d_in[18];
  const float* mw2   = (const float*)d_in[19];
  const float* mb2   = (const float*)d_in[20];
  const float* bng   = (const float*)d_in[21];
  const float* bnb   = (const float*)d_in[22];
  const float* bnm   = (const float*)d_in[23];
  const float* bnv   = (const float*)d_in[24];
  const float* paw1  = (const float*)d_in[25];
  const float* pab1  = (const float*)d_in[26];
  const float* paw2  = (const float*)d_in[27];
  const float* pab2  = (const float*)d_in[28];
  const float* caw1  = (const float*)d_in[29];
  const float* cab1  = (const float*)d_in[30];
  const float* caw2  = (const float*)d_in[31];
  const float* cab2  = (const float*)d_in[32];
  const float* aw1   = (const float*)d_in[33];
  const float* ab1   = (const float*)d_in[34];
  const float* aw2   = (const float*)d_in[35];
  const float* ab2   = (const float*)d_in[36];

  float* ws  = (float*)d_ws;
  float* out = (float*)d_out;
  float* st0 = ws + WS_STATS;
  float* st1 = st0 + 8;
  float* st2 = st0 + 16;
  unsigned short* ypm   = (unsigned short*)(ws + WS_YPM);
  float* q   = ws + WS_Q;
  float* k   = ws + WS_K;
  float* v   = ws + WS_V;
  unsigned short* attpm = (unsigned short*)(ws + WS_ATTPM);
  unsigned short* hid   = (unsigned short*)(ws + WS_Q);   // stage-3 reuse
  unsigned short* tpm   = (unsigned short*)(ws + WS_Q);   // stage-4 reuse
  float* x1  = ws + WS_X1;
  float* x2  = ws + WS_X2;
  float* x3  = ws + WS_X3;
  float* pab = ws + WS_PA;
  float* gpb = ws + WS_GAP;
  float* cab = ws + WS_CA;
  float* bns = ws + WBNS;

  hipMemsetAsync(d_ws, 0, 64*sizeof(float), stream);
  prep_weights<<<653, 256, 0, stream>>>(qkv1w, qkv2w, proj1w, proj2w, mw1, mw2, aw1, aw2,
                                        paw1, bng, bnb, bnm, bnv, ws);

  // stage 1: attn k=7 d=1
  stats_kernel<<<384, 256, 0, stream>>>(x, st0);
  ln_tr_kernel<<<256, 256, 0, stream>>>(x, st0, lnw, lnb, (unsigned int*)ypm);
  gemm_qkv_kernel<<<dim3(128,6), 256, 0, stream>>>(ypm, (unsigned short*)(ws+WQKV1), qkv1b, q, k, v);
  attn_kernel<7,1,13><<<1536, 256, 0, stream>>>(q, k, v, rpb1, attpm);
  gemm_proj_kernel<<<dim3(128,2), 256, 0, stream>>>(attpm, (unsigned short*)(ws+WPROJ1), proj1b,
                                                    x, st0, m1w, m1b, m2w, m2b, x1, st1);

  // stage 2: attn k=5 d=8
  ln_tr_kernel<<<256, 256, 0, stream>>>(x1, st1, lnw, lnb, (unsigned int*)ypm);
  gemm_qkv_kernel<<<dim3(128,6), 256, 0, stream>>>(ypm, (unsigned short*)(ws+WQKV2), qkv2b, q, k, v);
  attn_kernel<5,8,9><<<1536, 256, 0, stream>>>(q, k, v, rpb2, attpm);
  gemm_proj_kernel<<<dim3(128,2), 256, 0, stream>>>(attpm, (unsigned short*)(ws+WPROJ2), proj2b,
                                                    x1, st1, m1w, m1b, m2w, m2b, x2, st2);

  // stage 3: MLP (sc = x1)
  ln_tr_kernel<<<256, 256, 0, stream>>>(x2, st2, lnw, lnb, (unsigned int*)ypm);
  gemm_mlp1_kernel<<<dim3(128,8), 256, 0, stream>>>(ypm, (unsigned short*)(ws+WMLP1), mb1, hid);
  gemm_mlp2_kernel<<<dim3(128,2), 256, 0, stream>>>(hid, (unsigned short*)(ws+WMLP2), mb2,
                                                    x1, st2, m1w, m1b, m2w, m2b, x3);

  // stage 4: BN(fused) + pixel/channel attention + m2a + final residual (sc = x3)
  pa_kernel<<<256, 64, 0, stream>>>(x3, bns, ws + WPA1T, pab1, paw2, pab2, pab);
  gap_kernel<<<384, 256, 0, stream>>>(x3, bns, pab, gpb);
  ca_kernel<<<4, 128, 0, stream>>>(gpb, caw1, cab1, caw2, cab2, cab);
  y3_tr_kernel<<<256, 256, 0, stream>>>(x3, bns, pab, cab, (unsigned int*)ypm);
  gemm_m2a1_kernel<<<dim3(128,2), 256, 0, stream>>>(ypm, (unsigned short*)(ws+WM2A1), ab1, tpm);
  gemm_m2a2_kernel<<<dim3(128,2), 256, 0, stream>>>(tpm, (unsigned short*)(ws+WM2A2), ab2, x3, out);
}

// Round 6
// 305.454 us; speedup vs baseline: 1.5375x; 1.0060x over previous
//
#include <hip/hip_runtime.h>
#include <math.h>

#define CC 96
#define NP 4096
#define NHEADS 6
#define NELEMF 393216.0f
#define EPSF 1e-5f

typedef __attribute__((ext_vector_type(8))) short bf16x8;
typedef __attribute__((ext_vector_type(4))) float f32x4;
#define MFMA16(a,b,c) __builtin_amdgcn_mfma_f32_16x16x32_bf16(a,b,c,0,0,0)

// ---- workspace layout (float offsets) ----
#define WS_STATS 0
#define WQKV1  64
#define WQKV2  (WQKV1+13824)
#define WPROJ1 (WQKV2+13824)
#define WPROJ2 (WPROJ1+4608)
#define WMLP1  (WPROJ2+4608)
#define WMLP2  (WMLP1+18432)
#define WM2A1  (WMLP2+18432)
#define WM2A2  (WM2A1+4608)
#define WPA1T  (WM2A2+4608)
#define WBNS   (WPA1T+1152)
#define WS_YPM 84352
#define WS_Q   870784
#define WS_K   (WS_Q+786432)      // q/k/v now bf16: 786432 floats of space each
#define WS_V   (WS_K+786432)
#define WS_ATTPM (WS_V+786432)
#define WS_X1  (WS_ATTPM+786432)  // hid (bf16 16384x384) reuses WS_Q..WS_X1 exactly
#define WS_X2  (WS_X1+1572864)
#define WS_X3  (WS_X2+1572864)
#define WS_PA  (WS_X3+1572864)
#define WS_GAP (WS_PA+16384)
#define WS_CA  (WS_GAP+384)

__device__ __forceinline__ float gelu_f(float x){
  return 0.5f * x * (1.0f + erff(x * 0.7071067811865476f));
}
__device__ __forceinline__ float sigmoid_f(float x){
  return 1.0f / (1.0f + __expf(-x));
}
__device__ __forceinline__ unsigned short bfr(float f){
  unsigned int u = __float_as_uint(f);
  u += 0x7fffu + ((u >> 16) & 1u);
  return (unsigned short)(u >> 16);
}
__device__ __forceinline__ unsigned int bfpack(float a, float b){
  return (unsigned int)bfr(a) | ((unsigned int)bfr(b) << 16);
}
__device__ __forceinline__ float bflo(unsigned int u){ return __uint_as_float(u << 16); }
__device__ __forceinline__ float bfhi(unsigned int u){ return __uint_as_float(u & 0xffff0000u); }
__device__ __forceinline__ void get_ms(const float* st, int b, float& mean, float& inv, float& stdv){
  float s = st[b], s2 = st[4+b];
  mean = s * (1.0f/NELEMF);
  float var = fmaxf(s2 * (1.0f/NELEMF) - mean*mean, 0.0f);
  stdv = sqrtf(var + EPSF);
  inv = 1.0f / stdv;
}

// ---- per-batch sum/sumsq over input x ----
__global__ void stats_kernel(const float* __restrict__ src, float* __restrict__ st){
  int b = blockIdx.x / CC, c = blockIdx.x % CC;
  const float* p = src + (b*CC + c)*NP;
  float s = 0.f, s2 = 0.f;
  for(int i = threadIdx.x; i < NP; i += 256){ float v = p[i]; s += v; s2 = fmaf(v, v, s2); }
  for(int off = 32; off > 0; off >>= 1){ s += __shfl_down(s, off); s2 += __shfl_down(s2, off); }
  __shared__ float ls[8];
  int wid = threadIdx.x >> 6;
  if((threadIdx.x & 63) == 0){ ls[wid] = s; ls[4+wid] = s2; }
  __syncthreads();
  if(threadIdx.x == 0){
    atomicAdd(&st[b],   ls[0]+ls[1]+ls[2]+ls[3]);
    atomicAdd(&st[4+b], ls[4]+ls[5]+ls[6]+ls[7]);
  }
}

// ---- convert all weights to bf16 W^T[n][k]; BN scale/shift; pa1 transpose ----
__global__ void prep_weights(const float* __restrict__ q1, const float* __restrict__ q2,
                             const float* __restrict__ p1, const float* __restrict__ p2,
                             const float* __restrict__ w1, const float* __restrict__ w2,
                             const float* __restrict__ a1, const float* __restrict__ a2,
                             const float* __restrict__ pw1,
                             const float* __restrict__ bg, const float* __restrict__ bb,
                             const float* __restrict__ bm, const float* __restrict__ bv,
                             float* __restrict__ ws){
  int gid = blockIdx.x*256 + threadIdx.x;
  if(gid < 27648){ int n = gid/96, c = gid%96; ((unsigned short*)(ws+WQKV1))[gid] = bfr(q1[c*288+n]); }
  else if(gid < 55296){ int g = gid-27648; int n = g/96, c = g%96; ((unsigned short*)(ws+WQKV2))[g] = bfr(q2[c*288+n]); }
  else if(gid < 64512){ int g = gid-55296; int n = g/96, c = g%96; ((unsigned short*)(ws+WPROJ1))[g] = bfr(p1[c*96+n]); }
  else if(gid < 73728){ int g = gid-64512; int n = g/96, c = g%96; ((unsigned short*)(ws+WPROJ2))[g] = bfr(p2[c*96+n]); }
  else if(gid < 110592){ int g = gid-73728; ((unsigned short*)(ws+WMLP1))[g] = bfr(w1[g]); }
  else if(gid < 147456){ int g = gid-110592; ((unsigned short*)(ws+WMLP2))[g] = bfr(w2[g]); }
  else if(gid < 156672){ int g = gid-147456; ((unsigned short*)(ws+WM2A1))[g] = bfr(a1[g]); }
  else if(gid < 165888){ int g = gid-156672; ((unsigned short*)(ws+WM2A2))[g] = bfr(a2[g]); }
  else if(gid < 167040){ int g = gid-165888; int c = g/12, h = g%12; ws[WPA1T + g] = pw1[h*96+c]; }
  else if(gid < 167136){ int c = gid-167040;
    float sc = rsqrtf(bv[c] + EPSF) * bg[c];
    ws[WBNS + c] = sc;
    ws[WBNS + 96 + c] = bb[c] - bm[c]*sc;
  }
}

// ---- LN + transpose to pixel-major bf16: y[16384][96] ----
__global__ void __launch_bounds__(256) ln_tr_kernel(
    const float* __restrict__ src, const float* __restrict__ st,
    const float* __restrict__ lnw, const float* __restrict__ lnb,
    unsigned int* __restrict__ dst){
  int px0 = blockIdx.x*64; int b = px0 >> 12; int pxl0 = px0 & 4095;
  float mean, inv, stdv; get_ms(st, b, mean, inv, stdv);
  __shared__ float T[96*67];
  for(int idx = threadIdx.x; idx < 96*64; idx += 256){
    int c = idx >> 6, p = idx & 63;
    float s = inv*lnw[c]; float o = lnb[c] - mean*s;
    T[c*67 + p] = fmaf(src[(b*96 + c)*NP + pxl0 + p], s, o);
  }
  __syncthreads();
  for(int idx = threadIdx.x; idx < 64*48; idx += 256){
    int row = idx/48, cd = idx%48;
    dst[(px0 + row)*48 + cd] = bfpack(T[(2*cd)*67 + row], T[(2*cd+1)*67 + row]);
  }
}

// ---- BN*pa*ca + transpose to pixel-major bf16 (stage 4 m2a input) ----
__global__ void __launch_bounds__(256) y3_tr_kernel(
    const float* __restrict__ x3, const float* __restrict__ bns,
    const float* __restrict__ pa, const float* __restrict__ ca,
    unsigned int* __restrict__ dst){
  int px0 = blockIdx.x*64; int b = px0 >> 12; int pxl0 = px0 & 4095;
  __shared__ float T[96*67];
  for(int idx = threadIdx.x; idx < 96*64; idx += 256){
    int c = idx >> 6, p = idx & 63;
    float v = fmaf(x3[(b*96 + c)*NP + pxl0 + p], bns[c], bns[96 + c]);
    T[c*67 + p] = v * ca[b*96 + c] * pa[px0 + p];
  }
  __syncthreads();
  for(int idx = threadIdx.x; idx < 64*48; idx += 256){
    int row = idx/48, cd = idx%48;
    dst[(px0 + row)*48 + cd] = bfpack(T[(2*cd)*67 + row], T[(2*cd+1)*67 + row]);
  }
}

// ---- MFMA core: wave computes 32px x 48n, K-loop ----
template<int K>
__device__ __forceinline__ void mfma_tile(const unsigned short* __restrict__ A,
                                          const unsigned short* __restrict__ W,
                                          int m_base, int n_base, f32x4 acc[2][3]){
  int lane = threadIdx.x & 63;
  int ml = lane & 15, q = lane >> 4;
  const bf16x8* a0 = (const bf16x8*)(A + (size_t)(m_base + ml)*K + q*8);
  const bf16x8* a1 = (const bf16x8*)(A + (size_t)(m_base + 16 + ml)*K + q*8);
  const bf16x8* b0 = (const bf16x8*)(W + (n_base + ml)*K + q*8);
  const bf16x8* b1 = (const bf16x8*)(W + (n_base + 16 + ml)*K + q*8);
  const bf16x8* b2 = (const bf16x8*)(W + (n_base + 32 + ml)*K + q*8);
  #pragma unroll
  for(int ks = 0; ks < K/32; ++ks){
    bf16x8 av0 = a0[ks*4], av1 = a1[ks*4];
    bf16x8 bv0 = b0[ks*4], bv1 = b1[ks*4], bv2 = b2[ks*4];
    acc[0][0] = MFMA16(av0, bv0, acc[0][0]);
    acc[0][1] = MFMA16(av0, bv1, acc[0][1]);
    acc[0][2] = MFMA16(av0, bv2, acc[0][2]);
    acc[1][0] = MFMA16(av1, bv0, acc[1][0]);
    acc[1][1] = MFMA16(av1, bv1, acc[1][1]);
    acc[1][2] = MFMA16(av1, bv2, acc[1][2]);
  }
}

// ---- QKV GEMM: ypm @ WqkvT -> q/k/v bf16 [b,head,px,16] ----
__global__ void __launch_bounds__(256) gemm_qkv_kernel(
    const unsigned short* __restrict__ ypm, const unsigned short* __restrict__ wT,
    const float* __restrict__ qb,
    unsigned short* __restrict__ qo, unsigned short* __restrict__ ko, unsigned short* __restrict__ vo){
  int w = threadIdx.x >> 6, lane = threadIdx.x & 63;
  int ml = lane & 15, q = lane >> 4;
  int m_base = blockIdx.x*128 + w*32;
  int n0 = blockIdx.y*48;
  f32x4 acc[2][3];
  f32x4 z = {0.f,0.f,0.f,0.f};
  #pragma unroll
  for(int f=0; f<2; ++f) for(int g=0; g<3; ++g) acc[f][g] = z;
  mfma_tile<96>(ypm, wT, m_base, n0, acc);
  #pragma unroll
  for(int g = 0; g < 3; ++g){
    int nfb = n0 + g*16;
    int t = nfb/96, head = (nfb%96) >> 4;
    float scale = (t == 0) ? 0.25f : 1.0f;
    unsigned short* dst = (t == 0) ? qo : (t == 1) ? ko : vo;
    float bias = qb[nfb + ml];
    #pragma unroll
    for(int f = 0; f < 2; ++f){
      #pragma unroll
      for(int r = 0; r < 4; ++r){
        int m = m_base + f*16 + q*4 + r;
        int b = m >> 12, pxl = m & 4095;
        dst[(((size_t)(b*NHEADS + head))*NP + pxl)*16 + ml] = bfr((acc[f][g][r] + bias)*scale);
      }
    }
  }
}

// ---- proj GEMM: attpm @ projT -> c-major + residual + fused stats ----
__global__ void __launch_bounds__(256) gemm_proj_kernel(
    const unsigned short* __restrict__ attpm, const unsigned short* __restrict__ wT,
    const float* __restrict__ pb, const float* __restrict__ scx, const float* __restrict__ st,
    const float* __restrict__ m1w, const float* __restrict__ m1b,
    const float* __restrict__ m2w, const float* __restrict__ m2b,
    float* __restrict__ dst, float* __restrict__ st_out){
  int w = threadIdx.x >> 6, lane = threadIdx.x & 63;
  int ml = lane & 15, q = lane >> 4;
  int m_base = blockIdx.x*128 + w*32;
  int n0 = blockIdx.y*48;
  f32x4 acc[2][3];
  f32x4 z = {0.f,0.f,0.f,0.f};
  #pragma unroll
  for(int f=0; f<2; ++f) for(int g=0; g<3; ++g) acc[f][g] = z;
  mfma_tile<96>(attpm, wT, m_base, n0, acc);
  __shared__ float T[48*133];
  #pragma unroll
  for(int f = 0; f < 2; ++f)
    #pragma unroll
    for(int g = 0; g < 3; ++g)
      #pragma unroll
      for(int r = 0; r < 4; ++r)
        T[(g*16 + ml)*133 + w*32 + f*16 + q*4 + r] = acc[f][g][r];
  __syncthreads();
  int b = (blockIdx.x*128) >> 12, pxl0 = (blockIdx.x*128) & 4095;
  float mean, inv, stdv; get_ms(st, b, mean, inv, stdv);
  float s = 0.f, s2 = 0.f;
  for(int idx = threadIdx.x; idx < 48*128; idx += 256){
    int row = idx >> 7, px = idx & 127;
    int n = n0 + row;
    float rsf = fmaf(m1w[n], stdv, m1b[n]);
    float rbf = fmaf(m2w[n], mean, m2b[n]);
    int ad = (b*CC + n)*NP + pxl0 + px;
    float val = scx[ad] + (T[row*133 + px] + pb[n])*rsf + rbf;
    dst[ad] = val;
    s += val; s2 = fmaf(val, val, s2);
  }
  for(int off = 32; off > 0; off >>= 1){ s += __shfl_down(s, off); s2 += __shfl_down(s2, off); }
  __shared__ float ls[8];
  int wid = threadIdx.x >> 6;
  if((threadIdx.x & 63) == 0){ ls[wid] = s; ls[4+wid] = s2; }
  __syncthreads();
  if(threadIdx.x == 0){
    atomicAdd(&st_out[b],   ls[0]+ls[1]+ls[2]+ls[3]);
    atomicAdd(&st_out[4+b], ls[4]+ls[5]+ls[6]+ls[7]);
  }
}

// ---- mlp1 GEMM: ypm @ mlp1T -> relu -> hid pixel-major bf16 [16384][384] ----
__global__ void __launch_bounds__(256) gemm_mlp1_kernel(
    const unsigned short* __restrict__ ypm, const unsigned short* __restrict__ wT,
    const float* __restrict__ b1, unsigned short* __restrict__ hid){
  int w = threadIdx.x >> 6, lane = threadIdx.x & 63;
  int ml = lane & 15, q = lane >> 4;
  int m_base = blockIdx.x*128 + w*32;
  int n0 = blockIdx.y*48;
  f32x4 acc[2][3];
  f32x4 z = {0.f,0.f,0.f,0.f};
  #pragma unroll
  for(int f=0; f<2; ++f) for(int g=0; g<3; ++g) acc[f][g] = z;
  mfma_tile<96>(ypm, wT, m_base, n0, acc);
  #pragma unroll
  for(int g = 0; g < 3; ++g){
    int n = n0 + g*16 + ml;
    float bias = b1[n];
    #pragma unroll
    for(int f = 0; f < 2; ++f)
      #pragma unroll
      for(int r = 0; r < 4; ++r){
        int m = m_base + f*16 + q*4 + r;
        hid[(size_t)m*384 + n] = bfr(fmaxf(acc[f][g][r] + bias, 0.f));
      }
  }
}

// ---- mlp2 GEMM (K=384): hid @ mlp2T -> c-major + residual(x1) via st2 ----
__global__ void __launch_bounds__(256) gemm_mlp2_kernel(
    const unsigned short* __restrict__ hid, const unsigned short* __restrict__ wT,
    const float* __restrict__ b2, const float* __restrict__ scx, const float* __restrict__ st,
    const float* __restrict__ m1w, const float* __restrict__ m1b,
    const float* __restrict__ m2w, const float* __restrict__ m2b,
    float* __restrict__ dst){
  int w = threadIdx.x >> 6, lane = threadIdx.x & 63;
  int ml = lane & 15, q = lane >> 4;
  int m_base = blockIdx.x*128 + w*32;
  int n0 = blockIdx.y*48;
  f32x4 acc[2][3];
  f32x4 z = {0.f,0.f,0.f,0.f};
  #pragma unroll
  for(int f=0; f<2; ++f) for(int g=0; g<3; ++g) acc[f][g] = z;
  mfma_tile<384>(hid, wT, m_base, n0, acc);
  __shared__ float T[48*133];
  #pragma unroll
  for(int f = 0; f < 2; ++f)
    #pragma unroll
    for(int g = 0; g < 3; ++g)
      #pragma unroll
      for(int r = 0; r < 4; ++r)
        T[(g*16 + ml)*133 + w*32 + f*16 + q*4 + r] = acc[f][g][r];
  __syncthreads();
  int b = (blockIdx.x*128) >> 12, pxl0 = (blockIdx.x*128) & 4095;
  float mean, inv, stdv; get_ms(st, b, mean, inv, stdv);
  for(int idx = threadIdx.x; idx < 48*128; idx += 256){
    int row = idx >> 7, px = idx & 127;
    int n = n0 + row;
    float rsf = fmaf(m1w[n], stdv, m1b[n]);
    float rbf = fmaf(m2w[n], mean, m2b[n]);
    int ad = (b*CC + n)*NP + pxl0 + px;
    dst[ad] = scx[ad] + (T[row*133 + px] + b2[n])*rsf + rbf;
  }
}

// ---- fused m2a: y3pm @ W1 -> gelu (LDS) -> @ W2 -> + x3 -> out ----
__global__ void __launch_bounds__(256) gemm_m2a_kernel(
    const unsigned short* __restrict__ y3pm,
    const unsigned short* __restrict__ w1T, const float* __restrict__ b1,
    const unsigned short* __restrict__ w2T, const float* __restrict__ b2,
    const float* __restrict__ scx, float* __restrict__ outp){
  __shared__ __align__(16) char smbuf[128*104*2];
  unsigned short* tl = (unsigned short*)smbuf;
  float* T = (float*)smbuf;
  int w = threadIdx.x >> 6, lane = threadIdx.x & 63;
  int ml = lane & 15, q = lane >> 4;
  int m_base = blockIdx.x*128 + w*32;
  f32x4 z = {0.f,0.f,0.f,0.f};
  f32x4 acc[2][6];
  #pragma unroll
  for(int f=0; f<2; ++f) for(int g=0; g<6; ++g) acc[f][g] = z;
  {
    const bf16x8* a0 = (const bf16x8*)(y3pm + (size_t)(m_base + ml)*96 + q*8);
    const bf16x8* a1 = (const bf16x8*)(y3pm + (size_t)(m_base + 16 + ml)*96 + q*8);
    #pragma unroll
    for(int ks = 0; ks < 3; ++ks){
      bf16x8 av0 = a0[ks*4], av1 = a1[ks*4];
      #pragma unroll
      for(int g = 0; g < 6; ++g){
        bf16x8 bv = *(const bf16x8*)(w1T + (g*16 + ml)*96 + ks*32 + q*8);
        acc[0][g] = MFMA16(av0, bv, acc[0][g]);
        acc[1][g] = MFMA16(av1, bv, acc[1][g]);
      }
    }
  }
  #pragma unroll
  for(int g = 0; g < 6; ++g){
    float bias = b1[g*16 + ml];
    #pragma unroll
    for(int f = 0; f < 2; ++f)
      #pragma unroll
      for(int r = 0; r < 4; ++r)
        tl[(w*32 + f*16 + q*4 + r)*104 + g*16 + ml] = bfr(gelu_f(acc[f][g][r] + bias));
  }
  __syncthreads();
  f32x4 acc2[2][6];
  #pragma unroll
  for(int f=0; f<2; ++f) for(int g=0; g<6; ++g) acc2[f][g] = z;
  {
    const unsigned short* ar0 = tl + (w*32 + ml)*104;
    const unsigned short* ar1 = tl + (w*32 + 16 + ml)*104;
    #pragma unroll
    for(int ks = 0; ks < 3; ++ks){
      bf16x8 av0 = *(const bf16x8*)(ar0 + ks*32 + q*8);
      bf16x8 av1 = *(const bf16x8*)(ar1 + ks*32 + q*8);
      #pragma unroll
      for(int g = 0; g < 6; ++g){
        bf16x8 bv = *(const bf16x8*)(w2T + (g*16 + ml)*96 + ks*32 + q*8);
        acc2[0][g] = MFMA16(av0, bv, acc2[0][g]);
        acc2[1][g] = MFMA16(av1, bv, acc2[1][g]);
      }
    }
  }
  int b = (blockIdx.x*128) >> 12, pxl0 = (blockIdx.x*128) & 4095;
  #pragma unroll
  for(int half = 0; half < 2; ++half){
    __syncthreads();
    #pragma unroll
    for(int f = 0; f < 2; ++f)
      #pragma unroll
      for(int g = 0; g < 3; ++g)
        #pragma unroll
        for(int r = 0; r < 4; ++r)
          T[(g*16 + ml)*133 + w*32 + f*16 + q*4 + r] = acc2[f][half*3 + g][r];
    __syncthreads();
    for(int idx = threadIdx.x; idx < 48*128; idx += 256){
      int row = idx >> 7, px = idx & 127;
      int n = half*48 + row;
      int ad = (b*CC + n)*NP + pxl0 + px;
      outp[ad] = scx[ad] + T[row*133 + px] + b2[n];
    }
  }
}

// ---- neighborhood attention: bf16 LDS-staged k/v, output pixel-major bf16 ----
template<int K, int D, int RPB>
__global__ void __launch_bounds__(256) attn_kernel(
    const unsigned short* __restrict__ qb, const unsigned short* __restrict__ kb,
    const unsigned short* __restrict__ vb, const float* __restrict__ rpb,
    unsigned short* __restrict__ outp){
  int bh = blockIdx.x >> 6;
  int x = blockIdx.x & 63;
  int head = bh % NHEADS, b = bh / NHEADS;

  int gx = x % D, px = x / D;
  int Lgx = (64 - gx + D - 1) / D;
  int sx = min(max(px - K/2, 0), Lgx - K);

  __shared__ unsigned int sm[2*K*512];   // bf16 rows: 512 dwords per row
  unsigned int* kl = sm;
  unsigned int* vl = sm + K*512;
  const unsigned int* kg = (const unsigned int*)(kb + (size_t)bh*NP*16);
  const unsigned int* vg = (const unsigned int*)(vb + (size_t)bh*NP*16);
  int tid = threadIdx.x;
  #pragma unroll
  for(int i = 0; i < K; ++i){
    int hh = gx + D*(sx + i);
    ((uint2*)(kl + i*512))[tid] = ((const uint2*)(kg + hh*512))[tid];
    ((uint2*)(vl + i*512))[tid] = ((const uint2*)(vg + hh*512))[tid];
  }
  __syncthreads();

  int pixoff = tid >> 2, t = tid & 3;
  int y = pixoff;
  int pix = x*64 + y;
  uint2 qd = *(const uint2*)(qb + ((size_t)bh*NP + pix)*16 + 4*t);
  float qx = bflo(qd.x), qy = bfhi(qd.x), qz = bflo(qd.y), qw = bfhi(qd.y);

  int gy = y % D, py = y / D;
  int Lgy = (64 - gy + D - 1) / D;
  int sy = min(max(py - K/2, 0), Lgy - K);

  float sc[K*K];
  #pragma unroll
  for(int i = 0; i < K; ++i){
    #pragma unroll
    for(int j = 0; j < K; ++j){
      int ww = gy + D*(sy + j);
      uint2 kv = *(const uint2*)(kl + i*512 + ww*8 + t*2);
      float s = qx*bflo(kv.x);
      s = fmaf(qy, bfhi(kv.x), s);
      s = fmaf(qz, bflo(kv.y), s);
      s = fmaf(qw, bfhi(kv.y), s);
      sc[i*K + j] = s;
    }
  }
  float mx = -1e30f;
  #pragma unroll
  for(int i = 0; i < K; ++i){
    const float* brow = rpb + (head*RPB + (sx + i - px + (K-1)))*RPB + (sy - py + (K-1));
    #pragma unroll
    for(int j = 0; j < K; ++j){
      float s = sc[i*K + j];
      s += __shfl_xor(s, 1);
      s += __shfl_xor(s, 2);
      s += brow[j];
      sc[i*K + j] = s;
      mx = fmaxf(mx, s);
    }
  }
  float sum = 0.f;
  #pragma unroll
  for(int n = 0; n < K*K; ++n){ float e = __expf(sc[n] - mx); sc[n] = e; sum += e; }
  float rs = 1.0f / sum;
  float4 acc = {0,0,0,0};
  #pragma unroll
  for(int i = 0; i < K; ++i){
    #pragma unroll
    for(int j = 0; j < K; ++j){
      int ww = gy + D*(sy + j);
      float wgt = sc[i*K + j] * rs;
      uint2 vv = *(const uint2*)(vl + i*512 + ww*8 + t*2);
      acc.x = fmaf(wgt, bflo(vv.x), acc.x);
      acc.y = fmaf(wgt, bfhi(vv.x), acc.y);
      acc.z = fmaf(wgt, bflo(vv.y), acc.z);
      acc.w = fmaf(wgt, bfhi(vv.y), acc.w);
    }
  }
  ushort4 o4;
  o4.x = bfr(acc.x); o4.y = bfr(acc.y); o4.z = bfr(acc.z); o4.w = bfr(acc.w);
  *(ushort4*)(outp + ((size_t)(b*NP + pix))*96 + head*16 + 4*t) = o4;
}

// ---- pixel attention scalar map (BN fused), 256-thread blocks ----
__global__ void __launch_bounds__(256) pa_kernel(
    const float* __restrict__ x3, const float* __restrict__ bns,
    const float* __restrict__ w1t, const float* __restrict__ b1,
    const float* __restrict__ w2, const float* __restrict__ b2,
    float* __restrict__ pa){
  int b = blockIdx.x >> 4;
  int p = (blockIdx.x & 15)*256 + threadIdx.x;
  float acc[12];
  #pragma unroll
  for(int h = 0; h < 12; ++h) acc[h] = b1[h];
  #pragma unroll 8
  for(int c = 0; c < CC; ++c){
    float yv = fmaf(x3[(b*CC + c)*NP + p], bns[c], bns[96 + c]);
    #pragma unroll
    for(int h = 0; h < 12; ++h) acc[h] = fmaf(yv, w1t[c*12 + h], acc[h]);
  }
  float s = b2[0];
  #pragma unroll
  for(int h = 0; h < 12; ++h) s = fmaf(gelu_f(acc[h]), w2[h], s);
  pa[b*NP + p] = sigmoid_f(s);
}

// ---- global average pool of pa*BN(x3) ----
__global__ void gap_kernel(const float* __restrict__ x3, const float* __restrict__ bns,
                           const float* __restrict__ pa, float* __restrict__ gap){
  int b = blockIdx.x / CC, c = blockIdx.x % CC;
  float scb = bns[c], shb = bns[96 + c];
  float s = 0.f;
  for(int i = threadIdx.x; i < NP; i += 256)
    s = fmaf(fmaf(x3[(b*CC + c)*NP + i], scb, shb), pa[b*NP + i], s);
  for(int off = 32; off > 0; off >>= 1) s += __shfl_down(s, off);
  __shared__ float ls[4];
  if((threadIdx.x & 63) == 0) ls[threadIdx.x >> 6] = s;
  __syncthreads();
  if(threadIdx.x == 0) gap[blockIdx.x] = (ls[0]+ls[1]+ls[2]+ls[3]) * (1.0f/4096.0f);
}

// ---- channel attention ----
__global__ void ca_kernel(const float* __restrict__ gap, const float* __restrict__ w1,
                          const float* __restrict__ b1, const float* __restrict__ w2,
                          const float* __restrict__ b2, float* __restrict__ ca){
  int b = blockIdx.x; int o = threadIdx.x;
  __shared__ float g[96], t[96];
  if(o < 96) g[o] = gap[b*96 + o];
  __syncthreads();
  if(o < 96){
    float a = b1[o];
    for(int c = 0; c < 96; ++c) a = fmaf(g[c], w1[o*96 + c], a);
    t[o] = gelu_f(a);
  }
  __syncthreads();
  if(o < 96){
    float a = b2[o];
    for(int c = 0; c < 96; ++c) a = fmaf(t[c], w2[o*96 + c], a);
    ca[b*96 + o] = sigmoid_f(a);
  }
}

extern "C" void kernel_launch(void* const* d_in, const int* in_sizes, int n_in,
                              void* d_out, int out_size, void* d_ws, size_t ws_size,
                              hipStream_t stream){
  (void)in_sizes; (void)n_in; (void)out_size; (void)ws_size;
  const float* x     = (const float*)d_in[0];
  const float* lnw   = (const float*)d_in[1];
  const float* lnb   = (const float*)d_in[2];
  const float* m1w   = (const float*)d_in[3];
  const float* m1b   = (const float*)d_in[4];
  const float* m2w   = (const float*)d_in[5];
  const float* m2b   = (const float*)d_in[6];
  const float* qkv1w = (const float*)d_in[7];
  const float* qkv1b = (const float*)d_in[8];
  const float* proj1w= (const float*)d_in[9];
  const float* proj1b= (const float*)d_in[10];
  const float* rpb1  = (const float*)d_in[11];
  const float* qkv2w = (const float*)d_in[12];
  const float* qkv2b = (const float*)d_in[13];
  const float* proj2w= (const float*)d_in[14];
  const float* proj2b= (const float*)d_in[15];
  const float* rpb2  = (const float*)d_in[16];
  const float* mw1   = (const float*)d_in[17];
  const float* mb1   = (const float*)d_in[18];
  const float* mw2   = (const float*)d_in[19];
  const float* mb2   = (const float*)d_in[20];
  const float* bng   = (const float*)d_in[21];
  const float* bnb   = (const float*)d_in[22];
  const float* bnm   = (const float*)d_in[23];
  const float* bnv   = (const float*)d_in[24];
  const float* paw1  = (const float*)d_in[25];
  const float* pab1  = (const float*)d_in[26];
  const float* paw2  = (const float*)d_in[27];
  const float* pab2  = (const float*)d_in[28];
  const float* caw1  = (const float*)d_in[29];
  const float* cab1  = (const float*)d_in[30];
  const float* caw2  = (const float*)d_in[31];
  const float* cab2  = (const float*)d_in[32];
  const float* aw1   = (const float*)d_in[33];
  const float* ab1   = (const float*)d_in[34];
  const float* aw2   = (const float*)d_in[35];
  const float* ab2   = (const float*)d_in[36];

  float* ws  = (float*)d_ws;
  float* out = (float*)d_out;
  float* st0 = ws + WS_STATS;
  float* st1 = st0 + 8;
  float* st2 = st0 + 16;
  unsigned short* ypm   = (unsigned short*)(ws + WS_YPM);
  unsigned short* q     = (unsigned short*)(ws + WS_Q);
  unsigned short* k     = (unsigned short*)(ws + WS_K);
  unsigned short* v     = (unsigned short*)(ws + WS_V);
  unsigned short* attpm = (unsigned short*)(ws + WS_ATTPM);
  unsigned short* hid   = (unsigned short*)(ws + WS_Q);   // stage-3 reuse (q..attpm)
  float* x1  = ws + WS_X1;
  float* x2  = ws + WS_X2;
  float* x3  = ws + WS_X3;
  float* pab = ws + WS_PA;
  float* gpb = ws + WS_GAP;
  float* cab = ws + WS_CA;
  float* bns = ws + WBNS;

  hipMemsetAsync(d_ws, 0, 64*sizeof(float), stream);
  prep_weights<<<653, 256, 0, stream>>>(qkv1w, qkv2w, proj1w, proj2w, mw1, mw2, aw1, aw2,
                                        paw1, bng, bnb, bnm, bnv, ws);

  // stage 1: attn k=7 d=1
  stats_kernel<<<384, 256, 0, stream>>>(x, st0);
  ln_tr_kernel<<<256, 256, 0, stream>>>(x, st0, lnw, lnb, (unsigned int*)ypm);
  gemm_qkv_kernel<<<dim3(128,6), 256, 0, stream>>>(ypm, (unsigned short*)(ws+WQKV1), qkv1b, q, k, v);
  attn_kernel<7,1,13><<<1536, 256, 0, stream>>>(q, k, v, rpb1, attpm);
  gemm_proj_kernel<<<dim3(128,2), 256, 0, stream>>>(attpm, (unsigned short*)(ws+WPROJ1), proj1b,
                                                    x, st0, m1w, m1b, m2w, m2b, x1, st1);

  // stage 2: attn k=5 d=8
  ln_tr_kernel<<<256, 256, 0, stream>>>(x1, st1, lnw, lnb, (unsigned int*)ypm);
  gemm_qkv_kernel<<<dim3(128,6), 256, 0, stream>>>(ypm, (unsigned short*)(ws+WQKV2), qkv2b, q, k, v);
  attn_kernel<5,8,9><<<1536, 256, 0, stream>>>(q, k, v, rpb2, attpm);
  gemm_proj_kernel<<<dim3(128,2), 256, 0, stream>>>(attpm, (unsigned short*)(ws+WPROJ2), proj2b,
                                                    x1, st1, m1w, m1b, m2w, m2b, x2, st2);

  // stage 3: MLP (sc = x1)
  ln_tr_kernel<<<256, 256, 0, stream>>>(x2, st2, lnw, lnb, (unsigned int*)ypm);
  gemm_mlp1_kernel<<<dim3(128,8), 256, 0, stream>>>(ypm, (unsigned short*)(ws+WMLP1), mb1, hid);
  gemm_mlp2_kernel<<<dim3(128,2), 256, 0, stream>>>(hid, (unsigned short*)(ws+WMLP2), mb2,
                                                    x1, st2, m1w, m1b, m2w, m2b, x3);

  // stage 4: BN(fused) + pixel/channel attention + fused m2a + final residual (sc = x3)
  pa_kernel<<<64, 256, 0, stream>>>(x3, bns, ws + WPA1T, pab1, paw2, pab2, pab);
  gap_kernel<<<384, 256, 0, stream>>>(x3, bns, pab, gpb);
  ca_kernel<<<4, 128, 0, stream>>>(gpb, caw1, cab1, caw2, cab2, cab);
  y3_tr_kernel<<<256, 256, 0, stream>>>(x3, bns, pab, cab, (unsigned int*)ypm);
  gemm_m2a_kernel<<<128, 256, 0, stream>>>(ypm, (unsigned short*)(ws+WM2A1), ab1,
                                           (unsigned short*)(ws+WM2A2), ab2, x3, out);
}